// Round 1
// baseline (1046.794 us; speedup 1.0000x reference)
//
#include <hip/hip_runtime.h>
#include <hip/hip_bf16.h>
#include <type_traits>
#include <math.h>

#define DI __device__ __forceinline__

constexpr int NN   = 20000;
constexpr int NE   = 160000;
constexpr int FIN  = 64;
constexpr int HIDC = 256;
constexpr int NH   = 4;
constexpr int MQKV = NH * HIDC; // 1024

DI float bf2f(unsigned short u) { return __uint_as_float(((unsigned)u) << 16); }

// ---------------- CSR build ----------------
__global__ void k_count(const int* __restrict__ dst, int* __restrict__ deg, int e_) {
  int e = blockIdx.x * blockDim.x + threadIdx.x;
  if (e < e_) atomicAdd(&deg[dst[e]], 1);
}

__global__ void k_scan(const int* __restrict__ deg, int* __restrict__ offs,
                       int* __restrict__ cursor, int n_) {
  __shared__ int part[1024];
  int tid = threadIdx.x;
  const int CH = (n_ + 1023) >> 10;
  int base = tid * CH;
  int s = 0;
  for (int i = 0; i < CH; ++i) { int idx = base + i; if (idx < n_) s += deg[idx]; }
  part[tid] = s;
  __syncthreads();
  for (int off = 1; off < 1024; off <<= 1) {
    int v = (tid >= off) ? part[tid - off] : 0;
    __syncthreads();
    part[tid] += v;
    __syncthreads();
  }
  int run = (tid == 0) ? 0 : part[tid - 1];
  for (int i = 0; i < CH; ++i) {
    int idx = base + i;
    if (idx < n_) { offs[idx] = run; cursor[idx] = run; run += deg[idx]; }
  }
  if (tid == 1023) offs[n_] = run;
}

__global__ void k_scatter(const int* __restrict__ dst, int* __restrict__ cursor,
                          int* __restrict__ eid, int e_) {
  int e = blockIdx.x * blockDim.x + threadIdx.x;
  if (e < e_) {
    int p = atomicAdd(&cursor[dst[e]], 1);
    eid[p] = e;
  }
}

// ---------------- GEMM: out = X(nrows x K) @ W(K x M) + bias ----------------
template <typename OT>
__global__ __launch_bounds__(256) void k_gemm(
    const float* __restrict__ X, const float* __restrict__ W,
    const float* __restrict__ bias, OT* __restrict__ out,
    int nrows, int K, int M) {
  __shared__ float Xs[16][65];   // [k][row], padded
  __shared__ float Ws[16][64];   // [k][col]
  const int tid = threadIdx.x;
  const int bm = blockIdx.x * 64;
  const int bn = blockIdx.y * 64;
  const int tx = tid & 15, ty = tid >> 4;
  float acc[4][4] = {};
  for (int k0 = 0; k0 < K; k0 += 16) {
    {
      int r = tid >> 2;
      int kk = (tid & 3) << 2;
      float4 xv = make_float4(0.f, 0.f, 0.f, 0.f);
      int row = bm + r;
      if (row < nrows) xv = *(const float4*)(X + (size_t)row * K + k0 + kk);
      Xs[kk + 0][r] = xv.x; Xs[kk + 1][r] = xv.y;
      Xs[kk + 2][r] = xv.z; Xs[kk + 3][r] = xv.w;
    }
    {
      int kr = tid >> 4;
      int mc = (tid & 15) << 2;
      *(float4*)&Ws[kr][mc] = *(const float4*)(W + (size_t)(k0 + kr) * M + bn + mc);
    }
    __syncthreads();
#pragma unroll
    for (int k = 0; k < 16; ++k) {
      float a[4], b[4];
#pragma unroll
      for (int i = 0; i < 4; ++i) a[i] = Xs[k][ty * 4 + i];
#pragma unroll
      for (int j = 0; j < 4; ++j) b[j] = Ws[k][tx * 4 + j];
#pragma unroll
      for (int i = 0; i < 4; ++i)
#pragma unroll
        for (int j = 0; j < 4; ++j) acc[i][j] = fmaf(a[i], b[j], acc[i][j]);
    }
    __syncthreads();
  }
#pragma unroll
  for (int i = 0; i < 4; ++i) {
    int row = bm + ty * 4 + i;
    if (row < nrows) {
#pragma unroll
      for (int j = 0; j < 4; ++j) {
        int col = bn + tx * 4 + j;
        float v = acc[i][j] + bias[col];
        if constexpr (std::is_same<OT, __hip_bfloat16>::value)
          out[(size_t)row * M + col] = __float2bfloat16(v);
        else
          out[(size_t)row * M + col] = v;
      }
    }
  }
}

// ---------------- per-edge attention logits ----------------
__global__ __launch_bounds__(256) void k_alpha(
    const __hip_bfloat16* __restrict__ q, const __hip_bfloat16* __restrict__ k,
    const int* __restrict__ src, const int* __restrict__ dst,
    float* __restrict__ alpha, int e_) {
  int wv = threadIdx.x >> 6, lane = threadIdx.x & 63;
  int e = blockIdx.x * 4 + wv;
  if (e >= e_) return;
  const ushort* qb = (const ushort*)q + (size_t)dst[e] * MQKV;
  const ushort* kb = (const ushort*)k + (size_t)src[e] * MQKV;
#pragma unroll
  for (int h = 0; h < NH; ++h) {
    int c = h * HIDC + lane * 4;
    ushort4 qv = *(const ushort4*)(qb + c);
    ushort4 kv = *(const ushort4*)(kb + c);
    float p = bf2f(qv.x) * bf2f(kv.x) + bf2f(qv.y) * bf2f(kv.y)
            + bf2f(qv.z) * bf2f(kv.z) + bf2f(qv.w) * bf2f(kv.w);
#pragma unroll
    for (int off = 32; off > 0; off >>= 1) p += __shfl_xor(p, off);
    if (lane == 0) alpha[(size_t)e * NH + h] = p * 0.0625f; // 1/sqrt(256)
  }
}

// ---------------- per-node softmax + weighted aggregation (+skip already in xio) -----
__global__ __launch_bounds__(256) void k_aggregate(
    const __hip_bfloat16* __restrict__ v, const float* __restrict__ alpha,
    const int* __restrict__ offs, const int* __restrict__ eid,
    const int* __restrict__ src, float* __restrict__ xio) {
  int n = blockIdx.x;
  int s0 = offs[n], s1 = offs[n + 1];
  if (s1 == s0) return;  // no incoming edges: x stays = skip
  int h = threadIdx.x >> 6, lane = threadIdx.x & 63;
  __shared__ float denom_s[NH];
  __shared__ float red[NH][HIDC];
  float part = 0.f;
  for (int i = s0 + lane; i < s1; i += 64)
    part += expf(alpha[(size_t)eid[i] * NH + h]);
#pragma unroll
  for (int off = 32; off > 0; off >>= 1) part += __shfl_xor(part, off);
  if (lane == 0) denom_s[h] = part;
  __syncthreads();
  float dinv = 1.f / (denom_s[h] + 1e-16f);
  int c = lane * 4;
  float4 acc = make_float4(0.f, 0.f, 0.f, 0.f);
  const ushort* vb = (const ushort*)v;
  for (int i = s0; i < s1; ++i) {
    int e = eid[i];
    float w = expf(alpha[(size_t)e * NH + h]);
    const ushort* vr = vb + (size_t)src[e] * MQKV + h * HIDC + c;
    ushort4 vvv = *(const ushort4*)vr;
    acc.x = fmaf(w, bf2f(vvv.x), acc.x);
    acc.y = fmaf(w, bf2f(vvv.y), acc.y);
    acc.z = fmaf(w, bf2f(vvv.z), acc.z);
    acc.w = fmaf(w, bf2f(vvv.w), acc.w);
  }
  red[h][c + 0] = acc.x * dinv;
  red[h][c + 1] = acc.y * dinv;
  red[h][c + 2] = acc.z * dinv;
  red[h][c + 3] = acc.w * dinv;
  __syncthreads();
  if (threadIdx.x < 64) {
    int c0 = threadIdx.x * 4;
    float* xr = xio + (size_t)n * HIDC;
#pragma unroll
    for (int j = 0; j < 4; ++j) {
      float m = (red[0][c0 + j] + red[1][c0 + j] + red[2][c0 + j] + red[3][c0 + j]) * 0.25f;
      xr[c0 + j] = m + xr[c0 + j];
    }
  }
}

// ---------------- batch norm stats ----------------
__global__ void k_bnstats(const float* __restrict__ x, float* __restrict__ sums,
                          float* __restrict__ sumsq, int n_) {
  int t = threadIdx.x; // 256 threads = 256 features
  float s = 0.f, s2 = 0.f;
  for (int r = blockIdx.x; r < n_; r += gridDim.x) {
    float vv = x[(size_t)r * HIDC + t];
    s += vv; s2 += vv * vv;
  }
  atomicAdd(&sums[t], s);
  atomicAdd(&sumsq[t], s2);
}

__global__ void k_bnfin(const float* __restrict__ sums, const float* __restrict__ sumsq,
                        float* __restrict__ mu, float* __restrict__ rinv, int n_) {
  int t = threadIdx.x;
  float m = sums[t] / n_;
  float va = sumsq[t] / n_ - m * m;
  mu[t] = m;
  rinv[t] = 1.f / sqrtf(fmaxf(va, 0.f) + 1e-5f);
}

// ---------------- BN apply + linear head + softmax + rsu row ----------------
__global__ __launch_bounds__(64) void k_final(
    const float* __restrict__ x, const float* __restrict__ mu, const float* __restrict__ rinv,
    const float* __restrict__ gamma, const float* __restrict__ beta,
    const float* __restrict__ lw, const float* __restrict__ lb,
    float* __restrict__ out, int n_) {
  int n = blockIdx.x;
  int lane = threadIdx.x;
  int c = lane * 4;
  const float* xr = x + (size_t)n * HIDC;
  float4 xv = *(const float4*)(xr + c);
  float4 muv = *(const float4*)(mu + c);
  float4 rv  = *(const float4*)(rinv + c);
  float4 gv  = *(const float4*)(gamma + c);
  float4 bv  = *(const float4*)(beta + c);
  float y0 = gv.x * (xv.x - muv.x) * rv.x + bv.x;
  float y1 = gv.y * (xv.y - muv.y) * rv.y + bv.y;
  float y2 = gv.z * (xv.z - muv.z) * rv.z + bv.z;
  float y3 = gv.w * (xv.w - muv.w) * rv.w + bv.w;
  float4 wa = *(const float4*)(lw + (size_t)c * 2);       // w[c][0..1], w[c+1][0..1]
  float4 wb = *(const float4*)(lw + (size_t)c * 2 + 4);   // w[c+2][0..1], w[c+3][0..1]
  float p0 = y0 * wa.x + y1 * wa.z + y2 * wb.x + y3 * wb.z;
  float p1 = y0 * wa.y + y1 * wa.w + y2 * wb.y + y3 * wb.w;
#pragma unroll
  for (int off = 32; off > 0; off >>= 1) {
    p0 += __shfl_xor(p0, off);
    p1 += __shfl_xor(p1, off);
  }
  if (n == 0) *(float4*)(out + (size_t)NN * 2 + c) = make_float4(y0, y1, y2, y3);
  if (lane == 0) {
    float l0 = fmaxf(p0 + lb[0], 0.f);
    float l1 = fmaxf(p1 + lb[1], 0.f);
    float m = fmaxf(l0, l1);
    float e0 = expf(l0 - m), e1 = expf(l1 - m);
    float inv = 1.f / (e0 + e1);
    out[(size_t)n * 2 + 0] = e0 * inv;
    out[(size_t)n * 2 + 1] = e1 * inv;
  }
}

// ---------------- launch ----------------
extern "C" void kernel_launch(void* const* d_in, const int* in_sizes, int n_in,
                              void* d_out, int out_size, void* d_ws, size_t ws_size,
                              hipStream_t stream) {
  const float* x0  = (const float*)d_in[0];
  const int*   ei  = (const int*)d_in[1];
  const float* wq1 = (const float*)d_in[2];  const float* bq1 = (const float*)d_in[3];
  const float* wk1 = (const float*)d_in[4];  const float* bk1 = (const float*)d_in[5];
  const float* wv1 = (const float*)d_in[6];  const float* bv1 = (const float*)d_in[7];
  const float* ws1 = (const float*)d_in[8];  const float* bs1 = (const float*)d_in[9];
  const float* wq2 = (const float*)d_in[10]; const float* bq2 = (const float*)d_in[11];
  const float* wk2 = (const float*)d_in[12]; const float* bk2 = (const float*)d_in[13];
  const float* wv2 = (const float*)d_in[14]; const float* bv2 = (const float*)d_in[15];
  const float* ws2 = (const float*)d_in[16]; const float* bs2 = (const float*)d_in[17];
  const float* gam = (const float*)d_in[18]; const float* bet = (const float*)d_in[19];
  const float* lw  = (const float*)d_in[20]; const float* lb  = (const float*)d_in[21];
  const int* srcv = ei;
  const int* dstv = ei + NE;

  char* p = (char*)d_ws;
  auto take = [&](size_t bytes) {
    char* r = p;
    p += (bytes + 255) & ~(size_t)255;
    return r;
  };
  __hip_bfloat16* q  = (__hip_bfloat16*)take((size_t)NN * MQKV * 2);
  __hip_bfloat16* kk = (__hip_bfloat16*)take((size_t)NN * MQKV * 2);
  __hip_bfloat16* vv = (__hip_bfloat16*)take((size_t)NN * MQKV * 2);
  float* x2    = (float*)take((size_t)NN * HIDC * 4);
  float* x3    = (float*)take((size_t)NN * HIDC * 4);
  float* alpha = (float*)take((size_t)NE * NH * 4);
  float* bnbuf = (float*)take(4 * HIDC * 4);
  int* deg    = (int*)take((size_t)NN * 4);
  int* offs   = (int*)take((size_t)(NN + 1) * 4);
  int* cursor = (int*)take((size_t)NN * 4);
  int* eidb   = (int*)take((size_t)NE * 4);
  if ((size_t)(p - (char*)d_ws) > ws_size) return;  // ws too small: fail loudly (zero out)

  float* sums  = bnbuf;
  float* sumsq = bnbuf + HIDC;
  float* mu    = bnbuf + 2 * HIDC;
  float* rinv  = bnbuf + 3 * HIDC;

  hipMemsetAsync(deg, 0, (size_t)NN * 4, stream);
  hipMemsetAsync(bnbuf, 0, 2 * HIDC * 4, stream);
  k_count<<<(NE + 255) / 256, 256, 0, stream>>>(dstv, deg, NE);
  k_scan<<<1, 1024, 0, stream>>>(deg, offs, cursor, NN);
  k_scatter<<<(NE + 255) / 256, 256, 0, stream>>>(dstv, cursor, eidb, NE);

  dim3 blk(256);
  const int GR = (NN + 63) / 64; // 313
  // ---- layer 1 ----
  k_gemm<__hip_bfloat16><<<dim3(GR, MQKV / 64), blk, 0, stream>>>(x0, wq1, bq1, q,  NN, FIN, MQKV);
  k_gemm<__hip_bfloat16><<<dim3(GR, MQKV / 64), blk, 0, stream>>>(x0, wk1, bk1, kk, NN, FIN, MQKV);
  k_gemm<__hip_bfloat16><<<dim3(GR, MQKV / 64), blk, 0, stream>>>(x0, wv1, bv1, vv, NN, FIN, MQKV);
  k_gemm<float><<<dim3(GR, HIDC / 64), blk, 0, stream>>>(x0, ws1, bs1, x2, NN, FIN, HIDC);
  k_alpha<<<(NE + 3) / 4, blk, 0, stream>>>(q, kk, srcv, dstv, alpha, NE);
  k_aggregate<<<NN, blk, 0, stream>>>(vv, alpha, offs, eidb, srcv, x2);
  // ---- layer 2 ----
  k_gemm<__hip_bfloat16><<<dim3(GR, MQKV / 64), blk, 0, stream>>>(x2, wq2, bq2, q,  NN, HIDC, MQKV);
  k_gemm<__hip_bfloat16><<<dim3(GR, MQKV / 64), blk, 0, stream>>>(x2, wk2, bk2, kk, NN, HIDC, MQKV);
  k_gemm<__hip_bfloat16><<<dim3(GR, MQKV / 64), blk, 0, stream>>>(x2, wv2, bv2, vv, NN, HIDC, MQKV);
  k_gemm<float><<<dim3(GR, HIDC / 64), blk, 0, stream>>>(x2, ws2, bs2, x3, NN, HIDC, HIDC);
  k_alpha<<<(NE + 3) / 4, blk, 0, stream>>>(q, kk, srcv, dstv, alpha, NE);
  k_aggregate<<<NN, blk, 0, stream>>>(vv, alpha, offs, eidb, srcv, x3);
  // ---- BN + head ----
  k_bnstats<<<256, 256, 0, stream>>>(x3, sums, sumsq, NN);
  k_bnfin<<<1, HIDC, 0, stream>>>(sums, sumsq, mu, rinv, NN);
  k_final<<<NN, 64, 0, stream>>>(x3, mu, rinv, gam, bet, lw, lb, (float*)d_out, NN);
}

// Round 2
// 681.396 us; speedup vs baseline: 1.5362x; 1.5362x over previous
//
#include <hip/hip_runtime.h>
#include <hip/hip_bf16.h>
#include <math.h>

#define DI __device__ __forceinline__

constexpr int NN   = 20000;
constexpr int NE   = 160000;
constexpr int FIN  = 64;
constexpr int HIDC = 256;
constexpr int NH   = 4;
constexpr int NOUT = 3328;   // 3*1024 (QKV) + 256 (skip)
constexpr int QKVW = 3072;   // qkv columns per row

typedef __attribute__((ext_vector_type(8))) short short8;
typedef __attribute__((ext_vector_type(4))) float f32x4;

DI float bf2f(unsigned short u) { return __uint_as_float(((unsigned)u) << 16); }

DI void gld16(const void* g, void* l) {
  __builtin_amdgcn_global_load_lds((const __attribute__((address_space(1))) unsigned*)g,
                                   (__attribute__((address_space(3))) unsigned*)l, 16, 0, 0);
}

// ---------------- CSR build ----------------
__global__ void k_count(const int* __restrict__ dst, int* __restrict__ deg, int e_) {
  int e = blockIdx.x * blockDim.x + threadIdx.x;
  if (e < e_) atomicAdd(&deg[dst[e]], 1);
}

__global__ void k_scan(const int* __restrict__ deg, int* __restrict__ offs,
                       int* __restrict__ cursor, int n_) {
  __shared__ int part[1024];
  int tid = threadIdx.x;
  const int CH = (n_ + 1023) >> 10;
  int base = tid * CH;
  int s = 0;
  for (int i = 0; i < CH; ++i) { int idx = base + i; if (idx < n_) s += deg[idx]; }
  part[tid] = s;
  __syncthreads();
  for (int off = 1; off < 1024; off <<= 1) {
    int v = (tid >= off) ? part[tid - off] : 0;
    __syncthreads();
    part[tid] += v;
    __syncthreads();
  }
  int run = (tid == 0) ? 0 : part[tid - 1];
  for (int i = 0; i < CH; ++i) {
    int idx = base + i;
    if (idx < n_) { offs[idx] = run; cursor[idx] = run; run += deg[idx]; }
  }
  if (tid == 1023) offs[n_] = run;
}

__global__ void k_scatter(const int* __restrict__ dst, int* __restrict__ cursor,
                          int* __restrict__ eid, int e_) {
  int e = blockIdx.x * blockDim.x + threadIdx.x;
  if (e < e_) {
    int p = atomicAdd(&cursor[dst[e]], 1);
    eid[p] = e;
  }
}

// ---------------- input cast f32 -> bf16 ----------------
__global__ void k_cast(const float* __restrict__ x, __hip_bfloat16* __restrict__ xb, int n) {
  int i = blockIdx.x * 256 + threadIdx.x;
  if (i < n) xb[i] = __float2bfloat16(x[i]);
}

// ---------------- weight pack: Wt[n][k] = concat(wq|wk|wv|ws)[k][n], bf16 ----------------
template <int K>
__global__ void k_pack(const float* __restrict__ wq, const float* __restrict__ bq,
                       const float* __restrict__ wk, const float* __restrict__ bk,
                       const float* __restrict__ wv, const float* __restrict__ bv,
                       const float* __restrict__ ws, const float* __restrict__ bs,
                       __hip_bfloat16* __restrict__ Wt, float* __restrict__ biasp) {
  int n = blockIdx.x * 128 + threadIdx.x;  // 0..3327
  int k = blockIdx.y;                      // 0..K-1
  const float* w; const float* b; int off; int M;
  if (n < 1024)      { w = wq; b = bq; off = n;        M = 1024; }
  else if (n < 2048) { w = wk; b = bk; off = n - 1024; M = 1024; }
  else if (n < 3072) { w = wv; b = bv; off = n - 2048; M = 1024; }
  else               { w = ws; b = bs; off = n - 3072; M = 256;  }
  Wt[(size_t)n * K + k] = __float2bfloat16(w[(size_t)k * M + off]);
  if (k == 0) biasp[n] = b[off];
}

// ---------------- fused MFMA GEMM: [nrows x K] @ Wt^T -> qkv bf16 + skip f32 ----------------
// LDS layout per tile: chunks of 16B indexed [kb (k/8)][row], linear for global_load_lds.
template <int K>
__global__ __launch_bounds__(256) void k_gemm_mfma(
    const __hip_bfloat16* __restrict__ X, const __hip_bfloat16* __restrict__ Wt,
    const float* __restrict__ biasp,
    __hip_bfloat16* __restrict__ qkv, float* __restrict__ skip, int nrows) {
  __shared__ char lds[32768];  // 2 bufs x (A 8KB + B 8KB)
  const int tid = threadIdx.x;
  const int bm = blockIdx.x * 128;
  const int bn = blockIdx.y * 128;
  constexpr int KT = K / 32;

  // staging: thread t handles chunks t and t+256 of each tile (row = t&127, kb = t>>7 (+2))
  const int srow = tid & 127;
  int ar = bm + srow; if (ar >= nrows) ar = nrows - 1;
  const int br = bn + srow;
  const int kb0 = (tid >> 7) * 8;  // element offset 0 or 8
  const __hip_bfloat16* ax = X + (size_t)ar * K + kb0;
  const __hip_bfloat16* bx = Wt + (size_t)br * K + kb0;

  const int l = tid & 63, w = tid >> 6;
  const int wr = w >> 1, wc = w & 1;
  const int lm = l & 15, lk = l >> 4;
  const int aoff = (lk * 128 + wr * 64 + lm) * 16;
  const int boff = 8192 + (lk * 128 + wc * 64 + lm) * 16;

  f32x4 acc[4][4] = {};

  auto STAGE = [&](int buf, int kt) {
    char* base = lds + buf * 16384;
    const int ko = kt * 32;
    gld16(ax + ko,      base + tid * 16);
    gld16(ax + ko + 16, base + 4096 + tid * 16);
    gld16(bx + ko,      base + 8192 + tid * 16);
    gld16(bx + ko + 16, base + 12288 + tid * 16);
  };

  int cur = 0;
  STAGE(0, 0);
  __syncthreads();
#pragma unroll
  for (int kt = 0; kt < KT; ++kt) {
    if (kt + 1 < KT) STAGE(cur ^ 1, kt + 1);
    const char* base = lds + cur * 16384;
    short8 a[4], b[4];
#pragma unroll
    for (int m = 0; m < 4; ++m) a[m] = *(const short8*)(base + aoff + m * 256);
#pragma unroll
    for (int n = 0; n < 4; ++n) b[n] = *(const short8*)(base + boff + n * 256);
#pragma unroll
    for (int m = 0; m < 4; ++m)
#pragma unroll
      for (int n = 0; n < 4; ++n)
        acc[m][n] = __builtin_amdgcn_mfma_f32_16x16x32_bf16(a[m], b[n], acc[m][n], 0, 0, 0);
    __syncthreads();
    cur ^= 1;
  }

  // epilogue: row = bm + wr*64 + m*16 + lk*4 + r ; col = bn + wc*64 + n*16 + lm
  const int rbase = bm + wr * 64 + lk * 4;
  const int cb = bn + wc * 64 + lm;
  if (bn < QKVW) {
#pragma unroll
    for (int n = 0; n < 4; ++n) {
      int col = cb + n * 16;
      float bia = biasp[col];
#pragma unroll
      for (int m = 0; m < 4; ++m)
#pragma unroll
        for (int r = 0; r < 4; ++r) {
          int rr = rbase + m * 16 + r;
          if (rr < nrows) qkv[(size_t)rr * QKVW + col] = __float2bfloat16(acc[m][n][r] + bia);
        }
    }
  } else {
#pragma unroll
    for (int n = 0; n < 4; ++n) {
      int col = cb + n * 16;
      float bia = biasp[col];
      int sc = col - QKVW;
#pragma unroll
      for (int m = 0; m < 4; ++m)
#pragma unroll
        for (int r = 0; r < 4; ++r) {
          int rr = rbase + m * 16 + r;
          if (rr < nrows) skip[(size_t)rr * HIDC + sc] = acc[m][n][r] + bia;
        }
    }
  }
}

// ---------------- per-edge attention logits ----------------
__global__ __launch_bounds__(256) void k_alpha(
    const __hip_bfloat16* __restrict__ qkv,
    const int* __restrict__ src, const int* __restrict__ dst,
    float* __restrict__ alpha, int e_) {
  int wv = threadIdx.x >> 6, lane = threadIdx.x & 63;
  int e = blockIdx.x * 4 + wv;
  if (e >= e_) return;
  const ushort* qb = (const ushort*)qkv + (size_t)dst[e] * QKVW;
  const ushort* kb = (const ushort*)qkv + (size_t)src[e] * QKVW + 1024;
#pragma unroll
  for (int h = 0; h < NH; ++h) {
    int c = h * HIDC + lane * 4;
    ushort4 qv = *(const ushort4*)(qb + c);
    ushort4 kv = *(const ushort4*)(kb + c);
    float p = bf2f(qv.x) * bf2f(kv.x) + bf2f(qv.y) * bf2f(kv.y)
            + bf2f(qv.z) * bf2f(kv.z) + bf2f(qv.w) * bf2f(kv.w);
#pragma unroll
    for (int off = 32; off > 0; off >>= 1) p += __shfl_xor(p, off);
    if (lane == 0) alpha[(size_t)e * NH + h] = p * 0.0625f; // 1/sqrt(256)
  }
}

// ---------------- per-node softmax + aggregation (+skip already in xio) ----------------
__global__ __launch_bounds__(256) void k_aggregate(
    const __hip_bfloat16* __restrict__ qkv, const float* __restrict__ alpha,
    const int* __restrict__ offs, const int* __restrict__ eid,
    const int* __restrict__ src, float* __restrict__ xio,
    __hip_bfloat16* __restrict__ xb) {
  int n = blockIdx.x;
  int s0 = offs[n], s1 = offs[n + 1];
  int h = threadIdx.x >> 6, lane = threadIdx.x & 63;
  if (s1 == s0) {  // no incoming edges: x stays = skip; still emit bf16 copy
    if (xb != nullptr && threadIdx.x < 64) {
      int c = threadIdx.x * 4;
      const float* xr = xio + (size_t)n * HIDC;
#pragma unroll
      for (int j = 0; j < 4; ++j) xb[(size_t)n * HIDC + c + j] = __float2bfloat16(xr[c + j]);
    }
    return;
  }
  __shared__ float denom_s[NH];
  __shared__ float red[NH][HIDC];
  float part = 0.f;
  for (int i = s0 + lane; i < s1; i += 64)
    part += expf(alpha[(size_t)eid[i] * NH + h]);
#pragma unroll
  for (int off = 32; off > 0; off >>= 1) part += __shfl_xor(part, off);
  if (lane == 0) denom_s[h] = part;
  __syncthreads();
  float dinv = 1.f / (denom_s[h] + 1e-16f);
  int c = lane * 4;
  float4 acc = make_float4(0.f, 0.f, 0.f, 0.f);
  const ushort* vb = (const ushort*)qkv;
  for (int i = s0; i < s1; ++i) {
    int e = eid[i];
    float wgt = expf(alpha[(size_t)e * NH + h]);
    const ushort* vr = vb + (size_t)src[e] * QKVW + 2048 + h * HIDC + c;
    ushort4 vvv = *(const ushort4*)vr;
    acc.x = fmaf(wgt, bf2f(vvv.x), acc.x);
    acc.y = fmaf(wgt, bf2f(vvv.y), acc.y);
    acc.z = fmaf(wgt, bf2f(vvv.z), acc.z);
    acc.w = fmaf(wgt, bf2f(vvv.w), acc.w);
  }
  red[h][c + 0] = acc.x * dinv;
  red[h][c + 1] = acc.y * dinv;
  red[h][c + 2] = acc.z * dinv;
  red[h][c + 3] = acc.w * dinv;
  __syncthreads();
  if (threadIdx.x < 64) {
    int c0 = threadIdx.x * 4;
    float* xr = xio + (size_t)n * HIDC;
#pragma unroll
    for (int j = 0; j < 4; ++j) {
      float m = (red[0][c0 + j] + red[1][c0 + j] + red[2][c0 + j] + red[3][c0 + j]) * 0.25f;
      float val = m + xr[c0 + j];
      xr[c0 + j] = val;
      if (xb != nullptr) xb[(size_t)n * HIDC + c0 + j] = __float2bfloat16(val);
    }
  }
}

// ---------------- batch norm stats ----------------
__global__ void k_bnstats(const float* __restrict__ x, float* __restrict__ sums,
                          float* __restrict__ sumsq, int n_) {
  int t = threadIdx.x;
  float s = 0.f, s2 = 0.f;
  for (int r = blockIdx.x; r < n_; r += gridDim.x) {
    float vv = x[(size_t)r * HIDC + t];
    s += vv; s2 += vv * vv;
  }
  atomicAdd(&sums[t], s);
  atomicAdd(&sumsq[t], s2);
}

__global__ void k_bnfin(const float* __restrict__ sums, const float* __restrict__ sumsq,
                        float* __restrict__ mu, float* __restrict__ rinv, int n_) {
  int t = threadIdx.x;
  float m = sums[t] / n_;
  float va = sumsq[t] / n_ - m * m;
  mu[t] = m;
  rinv[t] = 1.f / sqrtf(fmaxf(va, 0.f) + 1e-5f);
}

// ---------------- BN apply + linear head + softmax + rsu row ----------------
__global__ __launch_bounds__(64) void k_final(
    const float* __restrict__ x, const float* __restrict__ mu, const float* __restrict__ rinv,
    const float* __restrict__ gamma, const float* __restrict__ beta,
    const float* __restrict__ lw, const float* __restrict__ lb,
    float* __restrict__ out, int n_) {
  int n = blockIdx.x;
  int lane = threadIdx.x;
  int c = lane * 4;
  const float* xr = x + (size_t)n * HIDC;
  float4 xv = *(const float4*)(xr + c);
  float4 muv = *(const float4*)(mu + c);
  float4 rv  = *(const float4*)(rinv + c);
  float4 gv  = *(const float4*)(gamma + c);
  float4 bv  = *(const float4*)(beta + c);
  float y0 = gv.x * (xv.x - muv.x) * rv.x + bv.x;
  float y1 = gv.y * (xv.y - muv.y) * rv.y + bv.y;
  float y2 = gv.z * (xv.z - muv.z) * rv.z + bv.z;
  float y3 = gv.w * (xv.w - muv.w) * rv.w + bv.w;
  float4 wa = *(const float4*)(lw + (size_t)c * 2);
  float4 wb = *(const float4*)(lw + (size_t)c * 2 + 4);
  float p0 = y0 * wa.x + y1 * wa.z + y2 * wb.x + y3 * wb.z;
  float p1 = y0 * wa.y + y1 * wa.w + y2 * wb.y + y3 * wb.w;
#pragma unroll
  for (int off = 32; off > 0; off >>= 1) {
    p0 += __shfl_xor(p0, off);
    p1 += __shfl_xor(p1, off);
  }
  if (n == 0) *(float4*)(out + (size_t)NN * 2 + c) = make_float4(y0, y1, y2, y3);
  if (lane == 0) {
    float l0 = fmaxf(p0 + lb[0], 0.f);
    float l1 = fmaxf(p1 + lb[1], 0.f);
    float m = fmaxf(l0, l1);
    float e0 = expf(l0 - m), e1 = expf(l1 - m);
    float inv = 1.f / (e0 + e1);
    out[(size_t)n * 2 + 0] = e0 * inv;
    out[(size_t)n * 2 + 1] = e1 * inv;
  }
}

// ---------------- launch ----------------
extern "C" void kernel_launch(void* const* d_in, const int* in_sizes, int n_in,
                              void* d_out, int out_size, void* d_ws, size_t ws_size,
                              hipStream_t stream) {
  const float* x0  = (const float*)d_in[0];
  const int*   ei  = (const int*)d_in[1];
  const float* wq1 = (const float*)d_in[2];  const float* bq1 = (const float*)d_in[3];
  const float* wk1 = (const float*)d_in[4];  const float* bk1 = (const float*)d_in[5];
  const float* wv1 = (const float*)d_in[6];  const float* bv1 = (const float*)d_in[7];
  const float* ws1 = (const float*)d_in[8];  const float* bs1 = (const float*)d_in[9];
  const float* wq2 = (const float*)d_in[10]; const float* bq2 = (const float*)d_in[11];
  const float* wk2 = (const float*)d_in[12]; const float* bk2 = (const float*)d_in[13];
  const float* wv2 = (const float*)d_in[14]; const float* bv2 = (const float*)d_in[15];
  const float* ws2 = (const float*)d_in[16]; const float* bs2 = (const float*)d_in[17];
  const float* gam = (const float*)d_in[18]; const float* bet = (const float*)d_in[19];
  const float* lw  = (const float*)d_in[20]; const float* lb  = (const float*)d_in[21];
  const int* srcv = ei;
  const int* dstv = ei + NE;

  char* p = (char*)d_ws;
  auto take = [&](size_t bytes) {
    char* r = p;
    p += (bytes + 255) & ~(size_t)255;
    return r;
  };
  __hip_bfloat16* qkv = (__hip_bfloat16*)take((size_t)NN * QKVW * 2);
  __hip_bfloat16* x0b = (__hip_bfloat16*)take((size_t)NN * FIN * 2);
  __hip_bfloat16* x2b = (__hip_bfloat16*)take((size_t)NN * HIDC * 2);
  __hip_bfloat16* Wt  = (__hip_bfloat16*)take((size_t)NOUT * HIDC * 2);
  float* x2    = (float*)take((size_t)NN * HIDC * 4);
  float* x3    = (float*)take((size_t)NN * HIDC * 4);
  float* alpha = (float*)take((size_t)NE * NH * 4);
  float* biasp = (float*)take((size_t)NOUT * 4);
  float* bnbuf = (float*)take(4 * HIDC * 4);
  int* deg    = (int*)take((size_t)NN * 4);
  int* offs   = (int*)take((size_t)(NN + 1) * 4);
  int* cursor = (int*)take((size_t)NN * 4);
  int* eidb   = (int*)take((size_t)NE * 4);
  if ((size_t)(p - (char*)d_ws) > ws_size) return;  // ws too small: output stays zero

  float* sums  = bnbuf;
  float* sumsq = bnbuf + HIDC;
  float* mu    = bnbuf + 2 * HIDC;
  float* rinv  = bnbuf + 3 * HIDC;

  hipMemsetAsync(deg, 0, (size_t)NN * 4, stream);
  hipMemsetAsync(bnbuf, 0, 2 * HIDC * 4, stream);
  k_count<<<(NE + 255) / 256, 256, 0, stream>>>(dstv, deg, NE);
  k_scan<<<1, 1024, 0, stream>>>(deg, offs, cursor, NN);
  k_scatter<<<(NE + 255) / 256, 256, 0, stream>>>(dstv, cursor, eidb, NE);
  k_cast<<<(NN * FIN + 255) / 256, 256, 0, stream>>>(x0, x0b, NN * FIN);

  const int RB = (NN + 127) / 128;  // 157
  const int CB = NOUT / 128;        // 26
  // ---- layer 1 ----
  k_pack<FIN><<<dim3(CB, FIN), 128, 0, stream>>>(wq1, bq1, wk1, bk1, wv1, bv1, ws1, bs1, Wt, biasp);
  k_gemm_mfma<FIN><<<dim3(RB, CB), 256, 0, stream>>>(x0b, Wt, biasp, qkv, x2, NN);
  k_alpha<<<(NE + 3) / 4, 256, 0, stream>>>(qkv, srcv, dstv, alpha, NE);
  k_aggregate<<<NN, 256, 0, stream>>>(qkv, alpha, offs, eidb, srcv, x2, x2b);
  // ---- layer 2 ----
  k_pack<HIDC><<<dim3(CB, HIDC), 128, 0, stream>>>(wq2, bq2, wk2, bk2, wv2, bv2, ws2, bs2, Wt, biasp);
  k_gemm_mfma<HIDC><<<dim3(RB, CB), 256, 0, stream>>>(x2b, Wt, biasp, qkv, x3, NN);
  k_alpha<<<(NE + 3) / 4, 256, 0, stream>>>(qkv, srcv, dstv, alpha, NE);
  k_aggregate<<<NN, 256, 0, stream>>>(qkv, alpha, offs, eidb, srcv, x3, nullptr);
  // ---- BN + head ----
  k_bnstats<<<256, 256, 0, stream>>>(x3, sums, sumsq, NN);
  k_bnfin<<<1, HIDC, 0, stream>>>(sums, sumsq, mu, rinv, NN);
  k_final<<<NN, 64, 0, stream>>>(x3, mu, rinv, gam, bet, lw, lb, (float*)d_out, NN);
}

// Round 3
// 462.928 us; speedup vs baseline: 2.2612x; 1.4719x over previous
//
#include <hip/hip_runtime.h>
#include <hip/hip_bf16.h>
#include <math.h>

#define DI __device__ __forceinline__

constexpr int NN   = 20000;
constexpr int NE   = 160000;
constexpr int FIN  = 64;
constexpr int HIDC = 256;
constexpr int NH   = 4;
constexpr int NOUT = 3328;   // 3*1024 (QKV) + 256 (skip)
constexpr int QKVW = 3072;   // qkv columns per row
constexpr int CAPD = 128;    // per-node edge stash capacity (slow path beyond)

typedef __attribute__((ext_vector_type(8))) short short8;
typedef __attribute__((ext_vector_type(4))) float f32x4;

DI float bf2f(unsigned short u) { return __uint_as_float(((unsigned)u) << 16); }

DI void gld16(const void* g, void* l) {
  __builtin_amdgcn_global_load_lds((const __attribute__((address_space(1))) unsigned*)g,
                                   (__attribute__((address_space(3))) unsigned*)l, 16, 0, 0);
}

// ---------------- CSR build ----------------
__global__ void k_count(const int* __restrict__ dst, int* __restrict__ deg, int e_) {
  int e = blockIdx.x * blockDim.x + threadIdx.x;
  if (e < e_) atomicAdd(&deg[dst[e]], 1);
}

__global__ void k_scan(const int* __restrict__ deg, int* __restrict__ offs,
                       int* __restrict__ cursor, int n_) {
  __shared__ int part[1024];
  int tid = threadIdx.x;
  const int CH = (n_ + 1023) >> 10;
  int base = tid * CH;
  int s = 0;
  for (int i = 0; i < CH; ++i) { int idx = base + i; if (idx < n_) s += deg[idx]; }
  part[tid] = s;
  __syncthreads();
  for (int off = 1; off < 1024; off <<= 1) {
    int v = (tid >= off) ? part[tid - off] : 0;
    __syncthreads();
    part[tid] += v;
    __syncthreads();
  }
  int run = (tid == 0) ? 0 : part[tid - 1];
  for (int i = 0; i < CH; ++i) {
    int idx = base + i;
    if (idx < n_) { offs[idx] = run; cursor[idx] = run; run += deg[idx]; }
  }
  if (tid == 1023) offs[n_] = run;
}

__global__ void k_scatter(const int* __restrict__ dst, int* __restrict__ cursor,
                          int* __restrict__ eid, int e_) {
  int e = blockIdx.x * blockDim.x + threadIdx.x;
  if (e < e_) {
    int p = atomicAdd(&cursor[dst[e]], 1);
    eid[p] = e;
  }
}

// ---------------- input cast f32 -> bf16 ----------------
__global__ void k_cast(const float* __restrict__ x, __hip_bfloat16* __restrict__ xb, int n) {
  int i = blockIdx.x * 256 + threadIdx.x;
  if (i < n) xb[i] = __float2bfloat16(x[i]);
}

// ---------------- weight pack: Wt[n][k] = concat(wq|wk|wv|ws)[k][n], bf16 ----------------
template <int K>
__global__ void k_pack(const float* __restrict__ wq, const float* __restrict__ bq,
                       const float* __restrict__ wk, const float* __restrict__ bk,
                       const float* __restrict__ wv, const float* __restrict__ bv,
                       const float* __restrict__ ws, const float* __restrict__ bs,
                       __hip_bfloat16* __restrict__ Wt, float* __restrict__ biasp) {
  int n = blockIdx.x * 128 + threadIdx.x;  // 0..3327
  int k = blockIdx.y;                      // 0..K-1
  const float* w; const float* b; int off; int M;
  if (n < 1024)      { w = wq; b = bq; off = n;        M = 1024; }
  else if (n < 2048) { w = wk; b = bk; off = n - 1024; M = 1024; }
  else if (n < 3072) { w = wv; b = bv; off = n - 2048; M = 1024; }
  else               { w = ws; b = bs; off = n - 3072; M = 256;  }
  Wt[(size_t)n * K + k] = __float2bfloat16(w[(size_t)k * M + off]);
  if (k == 0) biasp[n] = b[off];
}

// ---------------- fused MFMA GEMM: [nrows x K] @ Wt^T -> qkv bf16 + skip f32 ----------------
// Grid: 1D, row-major (col fastest) + bijective XCD chunk swizzle for L2 residency.
template <int K>
__global__ __launch_bounds__(256) void k_gemm_mfma(
    const __hip_bfloat16* __restrict__ X, const __hip_bfloat16* __restrict__ Wt,
    const float* __restrict__ biasp,
    __hip_bfloat16* __restrict__ qkv, float* __restrict__ skip, int nrows,
    int RB, int CB) {
  __shared__ char lds[36864];  // main loop: 2 bufs x 16KB; epilogue: 4 waves x 9216B
  const int tid = threadIdx.x;

  // bijective XCD swizzle (m204 variant): 8 XCDs, contiguous chunks
  const int nwg = RB * CB;
  int bid = blockIdx.x;
  {
    int q8 = nwg >> 3, r8 = nwg & 7;
    int xcd = bid & 7, idx = bid >> 3;
    bid = (xcd < r8 ? xcd * (q8 + 1) : r8 * (q8 + 1) + (xcd - r8) * q8) + idx;
  }
  const int bm = (bid / CB) * 128;
  const int bn = (bid % CB) * 128;
  constexpr int KT = K / 32;

  const int srow = tid & 127;
  int ar = bm + srow; if (ar >= nrows) ar = nrows - 1;
  const int br = bn + srow;
  const int kb0 = (tid >> 7) * 8;  // element offset 0 or 8
  const __hip_bfloat16* ax = X + (size_t)ar * K + kb0;
  const __hip_bfloat16* bx = Wt + (size_t)br * K + kb0;

  const int l = tid & 63, w = tid >> 6;
  const int wr = w >> 1, wc = w & 1;
  const int lm = l & 15, lk = l >> 4;
  const int aoff = (lk * 128 + wr * 64 + lm) * 16;
  const int boff = 8192 + (lk * 128 + wc * 64 + lm) * 16;

  f32x4 acc[4][4] = {};

  auto STAGE = [&](int buf, int kt) {
    char* base = lds + buf * 16384;
    const int ko = kt * 32;
    gld16(ax + ko,      base + tid * 16);
    gld16(ax + ko + 16, base + 4096 + tid * 16);
    gld16(bx + ko,      base + 8192 + tid * 16);
    gld16(bx + ko + 16, base + 12288 + tid * 16);
  };

  int cur = 0;
  STAGE(0, 0);
  __syncthreads();
#pragma unroll
  for (int kt = 0; kt < KT; ++kt) {
    if (kt + 1 < KT) STAGE(cur ^ 1, kt + 1);
    const char* base = lds + cur * 16384;
    short8 a[4], b[4];
#pragma unroll
    for (int m = 0; m < 4; ++m) a[m] = *(const short8*)(base + aoff + m * 256);
#pragma unroll
    for (int n = 0; n < 4; ++n) b[n] = *(const short8*)(base + boff + n * 256);
#pragma unroll
    for (int m = 0; m < 4; ++m)
#pragma unroll
      for (int n = 0; n < 4; ++n)
        acc[m][n] = __builtin_amdgcn_mfma_f32_16x16x32_bf16(a[m], b[n], acc[m][n], 0, 0, 0);
    __syncthreads();
    cur ^= 1;
  }

  // epilogue. acc[m][n][r] -> row_local = m*16+lk*4+r, col_local = n*16+lm
  if (bn < QKVW) {
    // stage wave's 64x64 bf16 tile into LDS (row stride 144B), then coalesced 16B stores
    char* wb = lds + w * 9216;
    float bia[4];
#pragma unroll
    for (int n = 0; n < 4; ++n) bia[n] = biasp[bn + wc * 64 + n * 16 + lm];
#pragma unroll
    for (int m = 0; m < 4; ++m)
#pragma unroll
      for (int n = 0; n < 4; ++n)
#pragma unroll
        for (int r = 0; r < 4; ++r) {
          int rl = m * 16 + lk * 4 + r;
          int cl = n * 16 + lm;
          *(__hip_bfloat16*)(wb + rl * 144 + cl * 2) = __float2bfloat16(acc[m][n][r] + bia[n]);
        }
    __syncthreads();  // also isolates from other waves' lds reuse
    const int c8 = l & 7;           // 8 lanes per row, 16B each
    const int r8 = l >> 3;          // 8 rows per iter
#pragma unroll
    for (int it = 0; it < 8; ++it) {
      int rl = it * 8 + r8;
      int grow = bm + wr * 64 + rl;
      if (grow < nrows) {
        short8 vvv = *(const short8*)(wb + rl * 144 + c8 * 16);
        *(short8*)((__hip_bfloat16*)qkv + (size_t)grow * QKVW + bn + wc * 64 + c8 * 8) = vvv;
      }
    }
  } else {
    const int rbase = bm + wr * 64 + lk * 4;
    const int cb = bn + wc * 64 + lm;
#pragma unroll
    for (int n = 0; n < 4; ++n) {
      int col = cb + n * 16;
      float bia = biasp[col];
      int sc = col - QKVW;
#pragma unroll
      for (int m = 0; m < 4; ++m)
#pragma unroll
        for (int r = 0; r < 4; ++r) {
          int rr = rbase + m * 16 + r;
          if (rr < nrows) skip[(size_t)rr * HIDC + sc] = acc[m][n][r] + bia;
        }
    }
  }
}

// ---------------- fused attention: per-node alpha + softmax + V aggregation ----------------
// xio holds skip (f32), updated in place; xb optional bf16 copy for next layer's GEMM.
__global__ __launch_bounds__(256) void k_attn(
    const __hip_bfloat16* __restrict__ qkv,
    const int* __restrict__ offs, const int* __restrict__ eid,
    const int* __restrict__ src, float* __restrict__ xio,
    __hip_bfloat16* __restrict__ xb) {
  int n = blockIdx.x;
  int s0 = offs[n], s1 = offs[n + 1];
  int deg = s1 - s0;
  int tid = threadIdx.x;
  if (deg == 0) {  // x stays = skip; still emit bf16 copy
    if (xb != nullptr && tid < 64) {
      int c = tid * 4;
      const float* xr = xio + (size_t)n * HIDC;
#pragma unroll
      for (int j = 0; j < 4; ++j) xb[(size_t)n * HIDC + c + j] = __float2bfloat16(xr[c + j]);
    }
    return;
  }
  __shared__ int ses[CAPD];
  __shared__ float ew[NH][CAPD];
  __shared__ float red[NH][HIDC];
  int h = tid >> 6, lane = tid & 63;
  int dc = deg < CAPD ? deg : CAPD;
  for (int i = tid; i < dc; i += 256) ses[i] = src[eid[s0 + i]];
  __syncthreads();

  const ushort* base = (const ushort*)qkv;
  int c = lane * 4;
  ushort4 q4 = *(const ushort4*)(base + (size_t)n * QKVW + h * HIDC + c);
  float qx = bf2f(q4.x), qy = bf2f(q4.y), qz = bf2f(q4.z), qw = bf2f(q4.w);

  // ---- pass 1: logits + denom ----
  float denom = 0.f;
  for (int i = 0; i < dc; ++i) {
    int s = ses[i];
    ushort4 k4 = *(const ushort4*)(base + (size_t)s * QKVW + 1024 + h * HIDC + c);
    float p = qx * bf2f(k4.x) + qy * bf2f(k4.y) + qz * bf2f(k4.z) + qw * bf2f(k4.w);
#pragma unroll
    for (int off = 32; off > 0; off >>= 1) p += __shfl_xor(p, off);
    float wgt = __expf(p * 0.0625f);
    if (lane == 0) ew[h][i] = wgt;
    denom += wgt;
  }
  for (int i = dc; i < deg; ++i) {  // slow path (deg > CAPD)
    int s = src[eid[s0 + i]];
    ushort4 k4 = *(const ushort4*)(base + (size_t)s * QKVW + 1024 + h * HIDC + c);
    float p = qx * bf2f(k4.x) + qy * bf2f(k4.y) + qz * bf2f(k4.z) + qw * bf2f(k4.w);
#pragma unroll
    for (int off = 32; off > 0; off >>= 1) p += __shfl_xor(p, off);
    denom += __expf(p * 0.0625f);
  }

  // ---- pass 2: weighted V sum ----
  float4 acc = make_float4(0.f, 0.f, 0.f, 0.f);
  for (int i = 0; i < dc; ++i) {
    int s = ses[i];
    float wgt = ew[h][i];
    ushort4 v4 = *(const ushort4*)(base + (size_t)s * QKVW + 2048 + h * HIDC + c);
    acc.x = fmaf(wgt, bf2f(v4.x), acc.x);
    acc.y = fmaf(wgt, bf2f(v4.y), acc.y);
    acc.z = fmaf(wgt, bf2f(v4.z), acc.z);
    acc.w = fmaf(wgt, bf2f(v4.w), acc.w);
  }
  for (int i = dc; i < deg; ++i) {  // slow path
    int s = src[eid[s0 + i]];
    ushort4 k4 = *(const ushort4*)(base + (size_t)s * QKVW + 1024 + h * HIDC + c);
    float p = qx * bf2f(k4.x) + qy * bf2f(k4.y) + qz * bf2f(k4.z) + qw * bf2f(k4.w);
#pragma unroll
    for (int off = 32; off > 0; off >>= 1) p += __shfl_xor(p, off);
    float wgt = __expf(p * 0.0625f);
    ushort4 v4 = *(const ushort4*)(base + (size_t)s * QKVW + 2048 + h * HIDC + c);
    acc.x = fmaf(wgt, bf2f(v4.x), acc.x);
    acc.y = fmaf(wgt, bf2f(v4.y), acc.y);
    acc.z = fmaf(wgt, bf2f(v4.z), acc.z);
    acc.w = fmaf(wgt, bf2f(v4.w), acc.w);
  }
  float dinv = 1.f / (denom + 1e-16f);
  red[h][c + 0] = acc.x * dinv;
  red[h][c + 1] = acc.y * dinv;
  red[h][c + 2] = acc.z * dinv;
  red[h][c + 3] = acc.w * dinv;
  __syncthreads();
  if (tid < 64) {
    int c0 = tid * 4;
    float* xr = xio + (size_t)n * HIDC;
#pragma unroll
    for (int j = 0; j < 4; ++j) {
      float m = (red[0][c0 + j] + red[1][c0 + j] + red[2][c0 + j] + red[3][c0 + j]) * 0.25f;
      float val = m + xr[c0 + j];
      xr[c0 + j] = val;
      if (xb != nullptr) xb[(size_t)n * HIDC + c0 + j] = __float2bfloat16(val);
    }
  }
}

// ---------------- batch norm stats ----------------
__global__ void k_bnstats(const float* __restrict__ x, float* __restrict__ sums,
                          float* __restrict__ sumsq, int n_) {
  int t = threadIdx.x;
  float s = 0.f, s2 = 0.f;
  for (int r = blockIdx.x; r < n_; r += gridDim.x) {
    float vv = x[(size_t)r * HIDC + t];
    s += vv; s2 += vv * vv;
  }
  atomicAdd(&sums[t], s);
  atomicAdd(&sumsq[t], s2);
}

__global__ void k_bnfin(const float* __restrict__ sums, const float* __restrict__ sumsq,
                        float* __restrict__ mu, float* __restrict__ rinv, int n_) {
  int t = threadIdx.x;
  float m = sums[t] / n_;
  float va = sumsq[t] / n_ - m * m;
  mu[t] = m;
  rinv[t] = 1.f / sqrtf(fmaxf(va, 0.f) + 1e-5f);
}

// ---------------- BN apply + linear head + softmax + rsu row ----------------
__global__ __launch_bounds__(64) void k_final(
    const float* __restrict__ x, const float* __restrict__ mu, const float* __restrict__ rinv,
    const float* __restrict__ gamma, const float* __restrict__ beta,
    const float* __restrict__ lw, const float* __restrict__ lb,
    float* __restrict__ out, int n_) {
  int n = blockIdx.x;
  int lane = threadIdx.x;
  int c = lane * 4;
  const float* xr = x + (size_t)n * HIDC;
  float4 xv = *(const float4*)(xr + c);
  float4 muv = *(const float4*)(mu + c);
  float4 rv  = *(const float4*)(rinv + c);
  float4 gv  = *(const float4*)(gamma + c);
  float4 bv  = *(const float4*)(beta + c);
  float y0 = gv.x * (xv.x - muv.x) * rv.x + bv.x;
  float y1 = gv.y * (xv.y - muv.y) * rv.y + bv.y;
  float y2 = gv.z * (xv.z - muv.z) * rv.z + bv.z;
  float y3 = gv.w * (xv.w - muv.w) * rv.w + bv.w;
  float4 wa = *(const float4*)(lw + (size_t)c * 2);
  float4 wb = *(const float4*)(lw + (size_t)c * 2 + 4);
  float p0 = y0 * wa.x + y1 * wa.z + y2 * wb.x + y3 * wb.z;
  float p1 = y0 * wa.y + y1 * wa.w + y2 * wb.y + y3 * wb.w;
#pragma unroll
  for (int off = 32; off > 0; off >>= 1) {
    p0 += __shfl_xor(p0, off);
    p1 += __shfl_xor(p1, off);
  }
  if (n == 0) *(float4*)(out + (size_t)NN * 2 + c) = make_float4(y0, y1, y2, y3);
  if (lane == 0) {
    float l0 = fmaxf(p0 + lb[0], 0.f);
    float l1 = fmaxf(p1 + lb[1], 0.f);
    float m = fmaxf(l0, l1);
    float e0 = expf(l0 - m), e1 = expf(l1 - m);
    float inv = 1.f / (e0 + e1);
    out[(size_t)n * 2 + 0] = e0 * inv;
    out[(size_t)n * 2 + 1] = e1 * inv;
  }
}

// ---------------- launch ----------------
extern "C" void kernel_launch(void* const* d_in, const int* in_sizes, int n_in,
                              void* d_out, int out_size, void* d_ws, size_t ws_size,
                              hipStream_t stream) {
  const float* x0  = (const float*)d_in[0];
  const int*   ei  = (const int*)d_in[1];
  const float* wq1 = (const float*)d_in[2];  const float* bq1 = (const float*)d_in[3];
  const float* wk1 = (const float*)d_in[4];  const float* bk1 = (const float*)d_in[5];
  const float* wv1 = (const float*)d_in[6];  const float* bv1 = (const float*)d_in[7];
  const float* ws1 = (const float*)d_in[8];  const float* bs1 = (const float*)d_in[9];
  const float* wq2 = (const float*)d_in[10]; const float* bq2 = (const float*)d_in[11];
  const float* wk2 = (const float*)d_in[12]; const float* bk2 = (const float*)d_in[13];
  const float* wv2 = (const float*)d_in[14]; const float* bv2 = (const float*)d_in[15];
  const float* ws2 = (const float*)d_in[16]; const float* bs2 = (const float*)d_in[17];
  const float* gam = (const float*)d_in[18]; const float* bet = (const float*)d_in[19];
  const float* lw  = (const float*)d_in[20]; const float* lb  = (const float*)d_in[21];
  const int* srcv = ei;
  const int* dstv = ei + NE;

  char* p = (char*)d_ws;
  auto take = [&](size_t bytes) {
    char* r = p;
    p += (bytes + 255) & ~(size_t)255;
    return r;
  };
  __hip_bfloat16* qkv = (__hip_bfloat16*)take((size_t)NN * QKVW * 2);
  __hip_bfloat16* x0b = (__hip_bfloat16*)take((size_t)NN * FIN * 2);
  __hip_bfloat16* x2b = (__hip_bfloat16*)take((size_t)NN * HIDC * 2);
  __hip_bfloat16* Wt  = (__hip_bfloat16*)take((size_t)NOUT * HIDC * 2);
  float* x2    = (float*)take((size_t)NN * HIDC * 4);
  float* x3    = (float*)take((size_t)NN * HIDC * 4);
  float* biasp = (float*)take((size_t)NOUT * 4);
  float* bnbuf = (float*)take(4 * HIDC * 4);
  int* deg    = (int*)take((size_t)NN * 4);
  int* offs   = (int*)take((size_t)(NN + 1) * 4);
  int* cursor = (int*)take((size_t)NN * 4);
  int* eidb   = (int*)take((size_t)NE * 4);
  if ((size_t)(p - (char*)d_ws) > ws_size) return;  // ws too small: output stays zero

  float* sums  = bnbuf;
  float* sumsq = bnbuf + HIDC;
  float* mu    = bnbuf + 2 * HIDC;
  float* rinv  = bnbuf + 3 * HIDC;

  hipMemsetAsync(deg, 0, (size_t)NN * 4, stream);
  hipMemsetAsync(bnbuf, 0, 2 * HIDC * 4, stream);
  k_count<<<(NE + 255) / 256, 256, 0, stream>>>(dstv, deg, NE);
  k_scan<<<1, 1024, 0, stream>>>(deg, offs, cursor, NN);
  k_scatter<<<(NE + 255) / 256, 256, 0, stream>>>(dstv, cursor, eidb, NE);
  k_cast<<<(NN * FIN + 255) / 256, 256, 0, stream>>>(x0, x0b, NN * FIN);

  const int RB = (NN + 127) / 128;  // 157
  const int CB = NOUT / 128;        // 26
  // ---- layer 1 ----
  k_pack<FIN><<<dim3(CB, FIN), 128, 0, stream>>>(wq1, bq1, wk1, bk1, wv1, bv1, ws1, bs1, Wt, biasp);
  k_gemm_mfma<FIN><<<RB * CB, 256, 0, stream>>>(x0b, Wt, biasp, qkv, x2, NN, RB, CB);
  k_attn<<<NN, 256, 0, stream>>>(qkv, offs, eidb, srcv, x2, x2b);
  // ---- layer 2 ----
  k_pack<HIDC><<<dim3(CB, HIDC), 128, 0, stream>>>(wq2, bq2, wk2, bk2, wv2, bv2, ws2, bs2, Wt, biasp);
  k_gemm_mfma<HIDC><<<RB * CB, 256, 0, stream>>>(x2b, Wt, biasp, qkv, x3, NN, RB, CB);
  k_attn<<<NN, 256, 0, stream>>>(qkv, offs, eidb, srcv, x3, nullptr);
  // ---- BN + head ----
  k_bnstats<<<256, 256, 0, stream>>>(x3, sums, sumsq, NN);
  k_bnfin<<<1, HIDC, 0, stream>>>(sums, sumsq, mu, rinv, NN);
  k_final<<<NN, 64, 0, stream>>>(x3, mu, rinv, gam, bet, lw, lb, (float*)d_out, NN);
}

// Round 4
// 413.471 us; speedup vs baseline: 2.5317x; 1.1196x over previous
//
#include <hip/hip_runtime.h>
#include <hip/hip_bf16.h>
#include <math.h>

#define DI __device__ __forceinline__

constexpr int NN   = 20000;
constexpr int NE   = 160000;
constexpr int FIN  = 64;
constexpr int HIDC = 256;
constexpr int NH   = 4;
constexpr int NOUT = 3328;   // 3*1024 (QKV) + 256 (skip)
constexpr int QKVW = 3072;   // qkv columns
constexpr int CAPD = 128;    // per-node edge index stash capacity

typedef __attribute__((ext_vector_type(8))) short short8;
typedef __attribute__((ext_vector_type(4))) float f32x4;
typedef __attribute__((ext_vector_type(2))) float f32x2;

DI float bf2f(unsigned short u) { return __uint_as_float(((unsigned)u) << 16); }

DI void gld16(const void* g, void* l) {
  __builtin_amdgcn_global_load_lds((const __attribute__((address_space(1))) unsigned*)g,
                                   (__attribute__((address_space(3))) unsigned*)l, 16, 0, 0);
}

DI unsigned fp8pack4(float a, float b, float c, float d) {
  int v = __builtin_amdgcn_cvt_pk_fp8_f32(a, b, 0, false);
  v = __builtin_amdgcn_cvt_pk_fp8_f32(c, d, v, true);
  return (unsigned)v;
}

// ---------------- CSR build ----------------
__global__ void k_count(const int* __restrict__ dst, int* __restrict__ deg, int e_) {
  int e = blockIdx.x * blockDim.x + threadIdx.x;
  if (e < e_) atomicAdd(&deg[dst[e]], 1);
}

__global__ void k_scan(const int* __restrict__ deg, int* __restrict__ offs,
                       int* __restrict__ cursor, int n_) {
  __shared__ int part[1024];
  int tid = threadIdx.x;
  const int CH = (n_ + 1023) >> 10;
  int base = tid * CH;
  int s = 0;
  for (int i = 0; i < CH; ++i) { int idx = base + i; if (idx < n_) s += deg[idx]; }
  part[tid] = s;
  __syncthreads();
  for (int off = 1; off < 1024; off <<= 1) {
    int v = (tid >= off) ? part[tid - off] : 0;
    __syncthreads();
    part[tid] += v;
    __syncthreads();
  }
  int run = (tid == 0) ? 0 : part[tid - 1];
  for (int i = 0; i < CH; ++i) {
    int idx = base + i;
    if (idx < n_) { offs[idx] = run; cursor[idx] = run; run += deg[idx]; }
  }
  if (tid == 1023) offs[n_] = run;
}

__global__ void k_scatter(const int* __restrict__ dst, int* __restrict__ cursor,
                          int* __restrict__ eid, int e_) {
  int e = blockIdx.x * blockDim.x + threadIdx.x;
  if (e < e_) {
    int p = atomicAdd(&cursor[dst[e]], 1);
    eid[p] = e;
  }
}

// ---------------- input cast f32 -> bf16 ----------------
__global__ void k_cast(const float* __restrict__ x, __hip_bfloat16* __restrict__ xb, int n) {
  int i = blockIdx.x * 256 + threadIdx.x;
  if (i < n) xb[i] = __float2bfloat16(x[i]);
}

// ---------------- weight pack: Wt[n][k] = concat(wq|wk|wv|ws)[k][n], bf16 ----------------
template <int K>
__global__ void k_pack(const float* __restrict__ wq, const float* __restrict__ bq,
                       const float* __restrict__ wk, const float* __restrict__ bk,
                       const float* __restrict__ wv, const float* __restrict__ bv,
                       const float* __restrict__ ws, const float* __restrict__ bs,
                       __hip_bfloat16* __restrict__ Wt, float* __restrict__ biasp) {
  int n = blockIdx.x * 128 + threadIdx.x;  // 0..3327
  int k = blockIdx.y;                      // 0..K-1
  const float* w; const float* b; int off; int M;
  if (n < 1024)      { w = wq; b = bq; off = n;        M = 1024; }
  else if (n < 2048) { w = wk; b = bk; off = n - 1024; M = 1024; }
  else if (n < 3072) { w = wv; b = bv; off = n - 2048; M = 1024; }
  else               { w = ws; b = bs; off = n - 3072; M = 256;  }
  Wt[(size_t)n * K + k] = __float2bfloat16(w[(size_t)k * M + off]);
  if (k == 0) biasp[n] = b[off];
}

// ---------------- fused MFMA GEMM -> qb bf16 | kb,vb fp8 | skip f32 ----------------
template <int K>
__global__ __launch_bounds__(256) void k_gemm_mfma(
    const __hip_bfloat16* __restrict__ X, const __hip_bfloat16* __restrict__ Wt,
    const float* __restrict__ biasp,
    __hip_bfloat16* __restrict__ qb, unsigned char* __restrict__ kb,
    unsigned char* __restrict__ vb, float* __restrict__ skip, int nrows,
    int RB, int CB) {
  __shared__ char lds[36864];  // main loop: 2 bufs x 16KB; epilogue: 4 waves x 9216B
  const int tid = threadIdx.x;

  // bijective XCD chunk swizzle
  const int nwg = RB * CB;
  int bid = blockIdx.x;
  {
    int q8 = nwg >> 3, r8 = nwg & 7;
    int xcd = bid & 7, idx = bid >> 3;
    bid = (xcd < r8 ? xcd * (q8 + 1) : r8 * (q8 + 1) + (xcd - r8) * q8) + idx;
  }
  const int bm = (bid / CB) * 128;
  const int bn = (bid % CB) * 128;
  constexpr int KT = K / 32;

  const int srow = tid & 127;
  int ar = bm + srow; if (ar >= nrows) ar = nrows - 1;
  const int br = bn + srow;
  const int kb0 = (tid >> 7) * 8;
  const __hip_bfloat16* ax = X + (size_t)ar * K + kb0;
  const __hip_bfloat16* bx = Wt + (size_t)br * K + kb0;

  const int l = tid & 63, w = tid >> 6;
  const int wr = w >> 1, wc = w & 1;
  const int lm = l & 15, lk = l >> 4;
  const int aoff = (lk * 128 + wr * 64 + lm) * 16;
  const int boff = 8192 + (lk * 128 + wc * 64 + lm) * 16;

  f32x4 acc[4][4] = {};

  auto STAGE = [&](int buf, int kt) {
    char* base = lds + buf * 16384;
    const int ko = kt * 32;
    gld16(ax + ko,      base + tid * 16);
    gld16(ax + ko + 16, base + 4096 + tid * 16);
    gld16(bx + ko,      base + 8192 + tid * 16);
    gld16(bx + ko + 16, base + 12288 + tid * 16);
  };

  int cur = 0;
  STAGE(0, 0);
  __syncthreads();
#pragma unroll
  for (int kt = 0; kt < KT; ++kt) {
    if (kt + 1 < KT) STAGE(cur ^ 1, kt + 1);
    const char* base = lds + cur * 16384;
    short8 a[4], b[4];
#pragma unroll
    for (int m = 0; m < 4; ++m) a[m] = *(const short8*)(base + aoff + m * 256);
#pragma unroll
    for (int n = 0; n < 4; ++n) b[n] = *(const short8*)(base + boff + n * 256);
#pragma unroll
    for (int m = 0; m < 4; ++m)
#pragma unroll
      for (int n = 0; n < 4; ++n)
        acc[m][n] = __builtin_amdgcn_mfma_f32_16x16x32_bf16(a[m], b[n], acc[m][n], 0, 0, 0);
    __syncthreads();
    cur ^= 1;
  }

  // epilogue. acc[m][n][r] -> row_local = m*16+lk*4+r, col_local = n*16+lm
  if (bn < QKVW) {
    // stage wave's 64x64 bf16 (+bias) tile into LDS (row stride 144B)
    char* wb = lds + w * 9216;
    float bia[4];
#pragma unroll
    for (int n = 0; n < 4; ++n) bia[n] = biasp[bn + wc * 64 + n * 16 + lm];
#pragma unroll
    for (int m = 0; m < 4; ++m)
#pragma unroll
      for (int n = 0; n < 4; ++n)
#pragma unroll
        for (int r = 0; r < 4; ++r) {
          int rl = m * 16 + lk * 4 + r;
          int cl = n * 16 + lm;
          *(__hip_bfloat16*)(wb + rl * 144 + cl * 2) = __float2bfloat16(acc[m][n][r] + bia[n]);
        }
    __syncthreads();
    const int c8 = l & 7;           // 8 lanes per row, 8 cols each
    const int r8 = l >> 3;          // 8 rows per iter
#pragma unroll
    for (int it = 0; it < 8; ++it) {
      int rl = it * 8 + r8;
      int grow = bm + wr * 64 + rl;
      if (grow >= nrows) continue;
      short8 t = *(const short8*)(wb + rl * 144 + c8 * 16);
      if (bn < 1024) {
        int col = bn + wc * 64 + c8 * 8;
        *(short8*)(qb + (size_t)grow * 1024 + col) = t;
      } else {
        float f0 = bf2f((unsigned short)t[0]), f1 = bf2f((unsigned short)t[1]);
        float f2 = bf2f((unsigned short)t[2]), f3 = bf2f((unsigned short)t[3]);
        float f4 = bf2f((unsigned short)t[4]), f5 = bf2f((unsigned short)t[5]);
        float f6 = bf2f((unsigned short)t[6]), f7 = bf2f((unsigned short)t[7]);
        uint2 d;
        d.x = fp8pack4(f0, f1, f2, f3);
        d.y = fp8pack4(f4, f5, f6, f7);
        if (bn < 2048) {
          int col = bn - 1024 + wc * 64 + c8 * 8;
          *(uint2*)(kb + (size_t)grow * 1024 + col) = d;
        } else {
          int col = bn - 2048 + wc * 64 + c8 * 8;
          *(uint2*)(vb + (size_t)grow * 1024 + col) = d;
        }
      }
    }
  } else {
    const int rbase = bm + wr * 64 + lk * 4;
    const int cb = bn + wc * 64 + lm;
#pragma unroll
    for (int n = 0; n < 4; ++n) {
      int col = cb + n * 16;
      float bia = biasp[col];
      int sc = col - QKVW;
#pragma unroll
      for (int m = 0; m < 4; ++m)
#pragma unroll
        for (int r = 0; r < 4; ++r) {
          int rr = rbase + m * 16 + r;
          if (rr < nrows) skip[(size_t)rr * HIDC + sc] = acc[m][n][r] + bia;
        }
    }
  }
}

// ---------------- fused single-pass attention ----------------
__global__ __launch_bounds__(256) void k_attn(
    const __hip_bfloat16* __restrict__ qb, const unsigned char* __restrict__ kb,
    const unsigned char* __restrict__ vb,
    const int* __restrict__ offs, const int* __restrict__ eid,
    const int* __restrict__ src, float* __restrict__ xio,
    __hip_bfloat16* __restrict__ xb) {
  int n = blockIdx.x;
  int s0 = offs[n], s1 = offs[n + 1];
  int deg = s1 - s0;
  int tid = threadIdx.x;
  if (deg == 0) {  // x stays = skip; still emit bf16 copy
    if (xb != nullptr && tid < 64) {
      int c = tid * 4;
      const float* xr = xio + (size_t)n * HIDC;
#pragma unroll
      for (int j = 0; j < 4; ++j) xb[(size_t)n * HIDC + c + j] = __float2bfloat16(xr[c + j]);
    }
    return;
  }
  __shared__ int ses[CAPD];
  __shared__ float red[NH][HIDC];
  int h = tid >> 6, lane = tid & 63;
  int dc = deg < CAPD ? deg : CAPD;
  for (int i = tid; i < dc; i += 256) ses[i] = src[eid[s0 + i]];
  __syncthreads();

  const int hc = h * HIDC;
  int c = lane * 4;
  ushort4 q4 = *(const ushort4*)((const ushort*)qb + (size_t)n * 1024 + hc + c);
  float qx = bf2f(q4.x), qy = bf2f(q4.y), qz = bf2f(q4.z), qw = bf2f(q4.w);

  float denom = 0.f;
  float4 acc = make_float4(0.f, 0.f, 0.f, 0.f);
  for (int i = 0; i < deg; ++i) {
    int s = (i < CAPD) ? ses[i] : src[eid[s0 + i]];
    unsigned ku = *(const unsigned*)(kb + (size_t)s * 1024 + hc + c);
    unsigned vu = *(const unsigned*)(vb + (size_t)s * 1024 + hc + c);
    f32x2 k01 = __builtin_amdgcn_cvt_pk_f32_fp8(ku, false);
    f32x2 k23 = __builtin_amdgcn_cvt_pk_f32_fp8(ku, true);
    float p = qx * k01.x + qy * k01.y + qz * k23.x + qw * k23.y;
#pragma unroll
    for (int off = 32; off > 0; off >>= 1) p += __shfl_xor(p, off);
    float wgt = __expf(p * 0.0625f);
    denom += wgt;
    f32x2 v01 = __builtin_amdgcn_cvt_pk_f32_fp8(vu, false);
    f32x2 v23 = __builtin_amdgcn_cvt_pk_f32_fp8(vu, true);
    acc.x = fmaf(wgt, v01.x, acc.x);
    acc.y = fmaf(wgt, v01.y, acc.y);
    acc.z = fmaf(wgt, v23.x, acc.z);
    acc.w = fmaf(wgt, v23.y, acc.w);
  }
  float dinv = 1.f / (denom + 1e-16f);
  red[h][c + 0] = acc.x * dinv;
  red[h][c + 1] = acc.y * dinv;
  red[h][c + 2] = acc.z * dinv;
  red[h][c + 3] = acc.w * dinv;
  __syncthreads();
  if (tid < 64) {
    int c0 = tid * 4;
    float* xr = xio + (size_t)n * HIDC;
#pragma unroll
    for (int j = 0; j < 4; ++j) {
      float m = (red[0][c0 + j] + red[1][c0 + j] + red[2][c0 + j] + red[3][c0 + j]) * 0.25f;
      float val = m + xr[c0 + j];
      xr[c0 + j] = val;
      if (xb != nullptr) xb[(size_t)n * HIDC + c0 + j] = __float2bfloat16(val);
    }
  }
}

// ---------------- batch norm stats ----------------
__global__ void k_bnstats(const float* __restrict__ x, float* __restrict__ sums,
                          float* __restrict__ sumsq, int n_) {
  int t = threadIdx.x;
  float s = 0.f, s2 = 0.f;
  for (int r = blockIdx.x; r < n_; r += gridDim.x) {
    float vv = x[(size_t)r * HIDC + t];
    s += vv; s2 += vv * vv;
  }
  atomicAdd(&sums[t], s);
  atomicAdd(&sumsq[t], s2);
}

__global__ void k_bnfin(const float* __restrict__ sums, const float* __restrict__ sumsq,
                        float* __restrict__ mu, float* __restrict__ rinv, int n_) {
  int t = threadIdx.x;
  float m = sums[t] / n_;
  float va = sumsq[t] / n_ - m * m;
  mu[t] = m;
  rinv[t] = 1.f / sqrtf(fmaxf(va, 0.f) + 1e-5f);
}

// ---------------- BN apply + linear head + softmax + rsu row ----------------
__global__ __launch_bounds__(64) void k_final(
    const float* __restrict__ x, const float* __restrict__ mu, const float* __restrict__ rinv,
    const float* __restrict__ gamma, const float* __restrict__ beta,
    const float* __restrict__ lw, const float* __restrict__ lb,
    float* __restrict__ out, int n_) {
  int n = blockIdx.x;
  int lane = threadIdx.x;
  int c = lane * 4;
  const float* xr = x + (size_t)n * HIDC;
  float4 xv = *(const float4*)(xr + c);
  float4 muv = *(const float4*)(mu + c);
  float4 rv  = *(const float4*)(rinv + c);
  float4 gv  = *(const float4*)(gamma + c);
  float4 bv  = *(const float4*)(beta + c);
  float y0 = gv.x * (xv.x - muv.x) * rv.x + bv.x;
  float y1 = gv.y * (xv.y - muv.y) * rv.y + bv.y;
  float y2 = gv.z * (xv.z - muv.z) * rv.z + bv.z;
  float y3 = gv.w * (xv.w - muv.w) * rv.w + bv.w;
  float4 wa = *(const float4*)(lw + (size_t)c * 2);
  float4 wb = *(const float4*)(lw + (size_t)c * 2 + 4);
  float p0 = y0 * wa.x + y1 * wa.z + y2 * wb.x + y3 * wb.z;
  float p1 = y0 * wa.y + y1 * wa.w + y2 * wb.y + y3 * wb.w;
#pragma unroll
  for (int off = 32; off > 0; off >>= 1) {
    p0 += __shfl_xor(p0, off);
    p1 += __shfl_xor(p1, off);
  }
  if (n == 0) *(float4*)(out + (size_t)NN * 2 + c) = make_float4(y0, y1, y2, y3);
  if (lane == 0) {
    float l0 = fmaxf(p0 + lb[0], 0.f);
    float l1 = fmaxf(p1 + lb[1], 0.f);
    float m = fmaxf(l0, l1);
    float e0 = expf(l0 - m), e1 = expf(l1 - m);
    float inv = 1.f / (e0 + e1);
    out[(size_t)n * 2 + 0] = e0 * inv;
    out[(size_t)n * 2 + 1] = e1 * inv;
  }
}

// ---------------- launch ----------------
extern "C" void kernel_launch(void* const* d_in, const int* in_sizes, int n_in,
                              void* d_out, int out_size, void* d_ws, size_t ws_size,
                              hipStream_t stream) {
  const float* x0  = (const float*)d_in[0];
  const int*   ei  = (const int*)d_in[1];
  const float* wq1 = (const float*)d_in[2];  const float* bq1 = (const float*)d_in[3];
  const float* wk1 = (const float*)d_in[4];  const float* bk1 = (const float*)d_in[5];
  const float* wv1 = (const float*)d_in[6];  const float* bv1 = (const float*)d_in[7];
  const float* ws1 = (const float*)d_in[8];  const float* bs1 = (const float*)d_in[9];
  const float* wq2 = (const float*)d_in[10]; const float* bq2 = (const float*)d_in[11];
  const float* wk2 = (const float*)d_in[12]; const float* bk2 = (const float*)d_in[13];
  const float* wv2 = (const float*)d_in[14]; const float* bv2 = (const float*)d_in[15];
  const float* ws2 = (const float*)d_in[16]; const float* bs2 = (const float*)d_in[17];
  const float* gam = (const float*)d_in[18]; const float* bet = (const float*)d_in[19];
  const float* lw  = (const float*)d_in[20]; const float* lb  = (const float*)d_in[21];
  const int* srcv = ei;
  const int* dstv = ei + NE;

  char* p = (char*)d_ws;
  auto take = [&](size_t bytes) {
    char* r = p;
    p += (bytes + 255) & ~(size_t)255;
    return r;
  };
  __hip_bfloat16* qb = (__hip_bfloat16*)take((size_t)NN * 1024 * 2);
  unsigned char* kbuf = (unsigned char*)take((size_t)NN * 1024);
  unsigned char* vbuf = (unsigned char*)take((size_t)NN * 1024);
  __hip_bfloat16* x0b = (__hip_bfloat16*)take((size_t)NN * FIN * 2);
  __hip_bfloat16* x2b = (__hip_bfloat16*)take((size_t)NN * HIDC * 2);
  __hip_bfloat16* Wt  = (__hip_bfloat16*)take((size_t)NOUT * HIDC * 2);
  float* x2    = (float*)take((size_t)NN * HIDC * 4);
  float* x3    = (float*)take((size_t)NN * HIDC * 4);
  float* biasp = (float*)take((size_t)NOUT * 4);
  float* bnbuf = (float*)take(4 * HIDC * 4);
  int* deg    = (int*)take((size_t)NN * 4);
  int* offs   = (int*)take((size_t)(NN + 1) * 4);
  int* cursor = (int*)take((size_t)NN * 4);
  int* eidb   = (int*)take((size_t)NE * 4);
  if ((size_t)(p - (char*)d_ws) > ws_size) return;

  float* sums  = bnbuf;
  float* sumsq = bnbuf + HIDC;
  float* mu    = bnbuf + 2 * HIDC;
  float* rinv  = bnbuf + 3 * HIDC;

  hipMemsetAsync(deg, 0, (size_t)NN * 4, stream);
  hipMemsetAsync(bnbuf, 0, 2 * HIDC * 4, stream);
  k_count<<<(NE + 255) / 256, 256, 0, stream>>>(dstv, deg, NE);
  k_scan<<<1, 1024, 0, stream>>>(deg, offs, cursor, NN);
  k_scatter<<<(NE + 255) / 256, 256, 0, stream>>>(dstv, cursor, eidb, NE);
  k_cast<<<(NN * FIN + 255) / 256, 256, 0, stream>>>(x0, x0b, NN * FIN);

  const int RB = (NN + 127) / 128;  // 157
  const int CB = NOUT / 128;        // 26
  // ---- layer 1 ----
  k_pack<FIN><<<dim3(CB, FIN), 128, 0, stream>>>(wq1, bq1, wk1, bk1, wv1, bv1, ws1, bs1, Wt, biasp);
  k_gemm_mfma<FIN><<<RB * CB, 256, 0, stream>>>(x0b, Wt, biasp, qb, kbuf, vbuf, x2, NN, RB, CB);
  k_attn<<<NN, 256, 0, stream>>>(qb, kbuf, vbuf, offs, eidb, srcv, x2, x2b);
  // ---- layer 2 ----
  k_pack<HIDC><<<dim3(CB, HIDC), 128, 0, stream>>>(wq2, bq2, wk2, bk2, wv2, bv2, ws2, bs2, Wt, biasp);
  k_gemm_mfma<HIDC><<<RB * CB, 256, 0, stream>>>(x2b, Wt, biasp, qb, kbuf, vbuf, x3, NN, RB, CB);
  k_attn<<<NN, 256, 0, stream>>>(qb, kbuf, vbuf, offs, eidb, srcv, x3, nullptr);
  // ---- BN + head ----
  k_bnstats<<<256, 256, 0, stream>>>(x3, sums, sumsq, NN);
  k_bnfin<<<1, HIDC, 0, stream>>>(sums, sumsq, mu, rinv, NN);
  k_final<<<NN, 64, 0, stream>>>(x3, mu, rinv, gam, bet, lw, lb, (float*)d_out, NN);
}